// Round 12
// baseline (330.584 us; speedup 1.0000x reference)
//
#include <hip/hip_runtime.h>
#include <hip/hip_bf16.h>

#define DIV_UP(a,b) (((a)+(b)-1)/(b))

typedef __attribute__((ext_vector_type(8))) short short8;
typedef __attribute__((ext_vector_type(4))) float f32x4;

__device__ __forceinline__ ushort bf16_bits(float x) {
    return __builtin_bit_cast(ushort, __float2bfloat16(x));
}

// async global->LDS 16B DMA: LDS dest is wave-uniform base + lane*16,
// global src is per-lane (pre-swizzled source pattern, guide rule 21)
__device__ __forceinline__ void gload_lds16(const ushort* g, ushort* l) {
    __builtin_amdgcn_global_load_lds(
        (const __attribute__((address_space(1))) void*)g,
        (__attribute__((address_space(3))) void*)l, 16, 0, 0);
}

// ---------------------------------------------------------------------------
// Merged prep: halo-zero (act1/act2/vbuf) + all three weight repacks in ONE
// launch, partitioned by blockIdx range (saves 3 serial launch overheads).
// grid = CHI + 8 + 288 + 1152 blocks of 256 threads.
// ---------------------------------------------------------------------------
__global__ __launch_bounds__(256) void prep_kernel(
    uint4* __restrict__ act1, uint4* __restrict__ act2,
    float4* __restrict__ vbuf, int CHI,
    const float* __restrict__ c1_w, __hip_bfloat16* __restrict__ w1b,
    const float* __restrict__ c2_w, __hip_bfloat16* __restrict__ w2t,
    const float* __restrict__ c3_w, __hip_bfloat16* __restrict__ w3t) {
    const int tid = threadIdx.x;
    int bx = blockIdx.x;

    if (bx < CHI) {                       // ---- halo zero for image bx ----
        const int b = bx;
        const uint4 z = {0u, 0u, 0u, 0u};
        uint4* a1 = act1 + (size_t)b * 33800;     // 65*65*64 bf16
        for (int i = tid; i < 520; i += 256) a1[i] = z;
        for (int i = tid; i < 512; i += 256) {
            int r = (i >> 3) + 1;
            a1[r * 520 + (i & 7)] = z;
        }
        uint4* a2 = act2 + (size_t)b * 17424;     // 33*33*128 bf16
        for (int i = tid; i < 528; i += 256) a2[i] = z;
        for (int i = tid; i < 512; i += 256) {
            int r = (i >> 4) + 1;
            a2[r * 528 + (i & 15)] = z;
        }
        int idx = b * 256 + tid;
        float4 zf = {0.f, 0.f, 0.f, 0.f};
        if (idx < 16384) vbuf[idx] = zf;
        return;
    }
    bx -= CHI;

    if (bx < 8) {                         // ---- conv1 weights [64][32] ----
        int t = bx * 256 + tid;           // t < 2048
        int k  = t & 31;
        int oc = t >> 5;
        w1b[t] = (k < 27) ? __float2bfloat16(c1_w[oc * 27 + k])
                          : __float2bfloat16(0.f);
        return;
    }
    bx -= 8;

    const float* src;
    __hip_bfloat16* dst;
    int O, C, t;
    if (bx < 288) {                       // ---- conv2 weights repack ----
        src = c2_w; dst = w2t; O = 128; C = 64;
        t = bx * 256 + tid;               // t < 73728
    } else {                              // ---- conv3 weights repack ----
        src = c3_w; dst = w3t; O = 256; C = 128;
        t = (bx - 288) * 256 + tid;       // t < 294912
    }
    int e   = t & 7;
    int r   = t >> 3;
    int n   = r % O;
    int q   = r / O;
    int SEG = C >> 3;
    int sg  = q % SEG;
    int tap = q / SEG;
    dst[t] = __float2bfloat16(src[(n * C + sg * 8 + e) * 9 + tap]);
}

// ---------------------------------------------------------------------------
// conv1 as MFMA implicit-GEMM (round-4 proven version):
// async-DMA input stage -> reg im2col -> swizzled Al -> MFMA -> direct stores
// ---------------------------------------------------------------------------
__global__ __launch_bounds__(256) void conv1_mfma_kernel(
    const float* __restrict__ in,
    const __hip_bfloat16* __restrict__ wB,   // [64][32] bf16
    const float* __restrict__ bias,
    __hip_bfloat16* __restrict__ out) {
    const int tid  = threadIdx.x;
    const int lane = tid & 63;
    const int wv   = tid >> 6;
    const int l15  = lane & 15;
    const int quad = lane >> 4;
    const int tile = blockIdx.x;             // 0..15, 4 oh rows each
    const int b    = blockIdx.y;
    const int oh0  = tile << 2;

    __shared__ __align__(16) char smem[30208];
    float*  sx = (float*)smem;               // [27][128] fp32, row q = c*9+r
    ushort* Al = (ushort*)(smem + 13824);    // [256][32] bf16 swizzled, 16 KB

    const float* ip  = in + (size_t)b * 3 * 128 * 128;
    const int    ih0 = 2 * oh0 - 1;

    // stage 27 rows x 128 fp32 = 864 16B chunks, linear LDS dest
#pragma unroll
    for (int it = 0; it < 4; ++it) {
        int e = (it << 8) + tid;
        if (e < 864) {
            int q = e >> 5, k = e & 31;      // row q, chunk k
            int c = q / 9, r = q - c * 9;
            int row = ih0 + r;
            if (row < 0) row = 0;            // clamp; masked in im2col
            gload_lds16((const ushort*)(ip + c * 16384 + row * 128 + k * 4),
                        (ushort*)smem + (size_t)e * 8);
        }
    }
    __syncthreads();   // drains vmcnt -> input resident in LDS

    // reg im2col: thread owns px = tid; 27 taps from sx with edge masks
    const int px = tid, ohl = px >> 6, ow = px & 63;
    union { uint4 u4[4]; ushort us[32]; } rowv;
#pragma unroll
    for (int c = 0; c < 3; ++c)
#pragma unroll
        for (int kh = 0; kh < 3; ++kh) {
            const bool rok = (ih0 + 2 * ohl + kh) >= 0;
            const float* srow = sx + (c * 9 + 2 * ohl + kh) * 128;
#pragma unroll
            for (int kw = 0; kw < 3; ++kw) {
                int iw = 2 * ow + kw - 1;
                bool ok = rok && (iw >= 0);
                float x = srow[iw < 0 ? 0 : iw];
                rowv.us[c * 9 + kh * 3 + kw] = bf16_bits(ok ? x : 0.f);
            }
        }
#pragma unroll
    for (int k = 27; k < 32; ++k) rowv.us[k] = 0;
#pragma unroll
    for (int q = 0; q < 4; ++q)
        *(uint4*)(Al + px * 32 + (((q ^ (px >> 1)) & 3) << 3)) = rowv.u4[q];

    // weight fragment (4 KB table, L2-hot): af rows = oc
    short8 af[4], bf[4];
#pragma unroll
    for (int i = 0; i < 4; ++i)
        af[i] = __builtin_bit_cast(short8,
            *(const uint4*)(wB + ((i * 16 + l15) * 32 + quad * 8)));

    __syncthreads();   // Al visible (exchange itself is intra-wave)

#pragma unroll
    for (int j = 0; j < 4; ++j) {
        int p = wv * 64 + j * 16 + l15;
        bf[j] = __builtin_bit_cast(short8,
            *(const uint4*)(Al + p * 32 + (((quad ^ (p >> 1)) & 3) << 3)));
    }
    f32x4 acc[4][4];
#pragma unroll
    for (int i = 0; i < 4; ++i)
#pragma unroll
        for (int j = 0; j < 4; ++j)
            acc[i][j] = __builtin_amdgcn_mfma_f32_16x16x32_bf16(
                af[i], bf[j], (f32x4){0.f, 0.f, 0.f, 0.f}, 0, 0, 0);

    float4 bv[4];
#pragma unroll
    for (int i = 0; i < 4; ++i)
        bv[i] = *(const float4*)(bias + i * 16 + quad * 4);

    // direct stores: D frag (col=px=j*16+l15 wave-local, row=oc=i*16+quad*4+r)
    __hip_bfloat16* ob = out + (((size_t)b * 65 + oh0 + 1) * 65 + 1) * 64;
#pragma unroll
    for (int j = 0; j < 4; ++j) {
        const int oww = j * 16 + l15;
        __hip_bfloat16* op = ob + ((size_t)(wv * 65) + oww) * 64 + quad * 4;
#pragma unroll
        for (int i = 0; i < 4; ++i) {
            union { uint2 u2; ushort us[4]; } pk;
#pragma unroll
            for (int r = 0; r < 4; ++r)
                pk.us[r] = bf16_bits(
                    fmaxf(acc[i][j][r] + ((const float*)&bv[i])[r], 0.f));
            *(uint2*)(op + i * 16) = pk.u2;
        }
    }
}

// ---------------------------------------------------------------------------
// conv2 implicit-GEMM v4: same tile/stage/occupancy as the proven R8 version
// (2 oh x 32 ow, 41600 B LDS, 3 blocks/CU, full-3-bit XOR swizzle), but
// operands SWAPPED (weights = A => D rows = 4 consecutive oc per lane) so
// the epilogue is direct uint2 fragment stores (conv1's proven pattern):
// no Cs alias, no epilogue barriers, no epilogue LDS traffic.
// ---------------------------------------------------------------------------
__global__ __launch_bounds__(256, 3) void conv2_gemm_kernel(
    const __hip_bfloat16* __restrict__ act,
    const __hip_bfloat16* __restrict__ wtB,   // [tap][8][128][8]
    const float* __restrict__ bias,
    __hip_bfloat16* __restrict__ out) {
    const int tid  = threadIdx.x;
    const int lane = tid & 63;
    const int w    = tid >> 6;
    const int l15  = lane & 15;
    const int quad = lane >> 4;
    const int per  = gridDim.x >> 3;
    const int Mt   = (blockIdx.x & 7) * per + (blockIdx.x >> 3);
    const int bimg = Mt >> 4;
    const int oh0  = (Mt & 15) << 1;         // 2 output rows per tile

    __shared__ __align__(16) char smem[41600];   // 325 px * 128 B
    ushort* As = (ushort*)smem;

    f32x4 acc[4][2];
#pragma unroll
    for (int i = 0; i < 4; ++i)
#pragma unroll
        for (int j = 0; j < 2; ++j) acc[i][j] = (f32x4){0.f, 0.f, 0.f, 0.f};

    const int wm  = (w & 1) << 6;            // wave owns 64 oc (M)
    const int pxw = (w >> 1) << 5;           // wave owns 32 px (N)
    const size_t abase = ((size_t)(bimg * 65 + 2 * oh0)) * 65 * 64;
    const ushort* ap = (const ushort*)act;

    // stage 5 rows x 65 px x 64 ch = 2600 16B chunks, full lines.
    // dest chunk t of pixel p holds source chunk t^((p>>1)&7) (ch = 8*q)
#pragma unroll
    for (int it = 0; it < 11; ++it) {
        int c = (it << 8) + tid;
        if (c < 2600) {
            int p = c >> 3, t = c & 7;       // p = r*65 + px
            int q = t ^ ((p >> 1) & 7);
            gload_lds16(ap + abase + (size_t)p * 64 + q * 8,
                        As + (size_t)c * 8);
        }
    }
    __syncthreads();   // drains vmcnt -> tile resident in LDS

    for (int h = 0; h < 2; ++h) {
        const int q = h * 4 + quad;          // logical K-seg (8 ch each)
#pragma unroll
        for (int tap = 0; tap < 9; ++tap) {
            const int kh = tap / 3, kw = tap - kh * 3;
            short8 af[4], bf[2];
#pragma unroll
            for (int i = 0; i < 4; ++i)      // A = weights (64 oc per wave)
                af[i] = __builtin_bit_cast(short8,
                    *(const uint4*)(wtB +
                        ((size_t)((tap * 8 + h * 4 + quad) * 128) +
                         wm + i * 16 + l15) * 8));
#pragma unroll
            for (int j = 0; j < 2; ++j) {    // B = pixels (32 per wave)
                int px = pxw + j * 16 + l15;
                int p  = ((px >> 5) * 2 + kh) * 65 + ((px & 31) * 2 + kw);
                bf[j] = __builtin_bit_cast(short8,
                    *(const uint4*)(As + p * 64 +
                                    ((q ^ ((p >> 1) & 7)) << 3)));
            }
#pragma unroll
            for (int i = 0; i < 4; ++i)
#pragma unroll
                for (int j = 0; j < 2; ++j)
                    acc[i][j] = __builtin_amdgcn_mfma_f32_16x16x32_bf16(
                        af[i], bf[j], acc[i][j], 0, 0, 0);
        }
    }

    // direct stores: D row = oc = wm+i*16+quad*4+r (contiguous 4),
    // col = px = pxw+j*16+l15 -> uint2 per (i,j); 4 i-steps x 2 waves
    // fill each 256B pixel line (write-combined, conv1-proven pattern)
    float4 bv[4];
#pragma unroll
    for (int i = 0; i < 4; ++i)
        bv[i] = *(const float4*)(bias + wm + i * 16 + quad * 4);

#pragma unroll
    for (int j = 0; j < 2; ++j) {
        int pxl = pxw + j * 16 + l15;
        int ohl = pxl >> 5, ow = pxl & 31;
        __hip_bfloat16* op = out +
            (((size_t)(bimg * 33) + oh0 + ohl + 1) * 33 + (ow + 1)) * 128 +
            wm + quad * 4;
#pragma unroll
        for (int i = 0; i < 4; ++i) {
            union { uint2 u2; ushort us[4]; } pk;
#pragma unroll
            for (int r = 0; r < 4; ++r)
                pk.us[r] = bf16_bits(
                    fmaxf(acc[i][j][r] + ((const float*)&bv[i])[r], 0.f));
            *(uint2*)(op + i * 16) = pk.u2;
        }
    }
}

// ---------------------------------------------------------------------------
// conv3 implicit-GEMM + fused pool (round-4 proven version): full 128-ch
// A-tile staged ONCE via async global_load_lds (full 256B lines, linear
// dest, inverse-swizzled source), single barrier. Tap loop NOT unrolled.
// M-tile 64 px (4 oh x 16 ow), N = 256. LDS 304 px * 256 B = 77824 B.
// ---------------------------------------------------------------------------
__global__ __launch_bounds__(256, 2) void conv3_gemm_pool_kernel(
    const __hip_bfloat16* __restrict__ act,
    const __hip_bfloat16* __restrict__ wtB,   // [tap][16][256][8]
    const float* __restrict__ bias,
    float* __restrict__ v /* [CHI,256], pre-zeroed */) {
    const int tid  = threadIdx.x;
    const int lane = tid & 63;
    const int w    = tid >> 6;
    const int l15  = lane & 15;
    const int quad = lane >> 4;
    const int per  = gridDim.x >> 3;
    const int Mt   = (blockIdx.x & 7) * per + (blockIdx.x >> 3);
    const int bimg = Mt >> 2;
    const int oh0  = (Mt & 3) << 2;

    __shared__ __align__(16) char smem[77824];
    ushort* As   = (ushort*)smem;
    float*  sred = (float*)smem;                 // pool alias (1 KB)

    f32x4 acc[4][4];
#pragma unroll
    for (int i = 0; i < 4; ++i)
#pragma unroll
        for (int j = 0; j < 4; ++j) acc[i][j] = (f32x4){0.f, 0.f, 0.f, 0.f};

    const int wn = w << 6;                       // wave owns 64 n-cols
    const size_t abase = ((size_t)(bimg * 33 + 2 * oh0)) * 33 * 128;
    const ushort* ap = (const ushort*)act;

    // stage 297 px x 128 ch (9 rows x 33 px), 16 chunks/px, 4864 chunks total.
#pragma unroll
    for (int it = 0; it < 19; ++it) {
        int c  = (it << 8) + tid;
        int p  = c >> 4;                 // pixel
        int t  = c & 15;                 // dest chunk-in-px
        int h  = t >> 3;                 // 64-ch half
        int ss = (t & 7) ^ ((p >> 1) & 7);
        gload_lds16(ap + abase + (size_t)p * 128 + h * 64 + ss * 8,
                    As + (size_t)c * 8);
    }
    __syncthreads();   // drains vmcnt -> all of A resident in LDS

    for (int h = 0; h < 2; ++h) {
#pragma unroll 1
        for (int tap = 0; tap < 9; ++tap) {
            const int kh = tap / 3, kw = tap - kh * 3;
#pragma unroll
            for (int ks = 0; ks < 2; ++ks) {
                short8 af[4], bf[4];
                const int sl = ks * 4 + quad;        // seg within 64-ch half
#pragma unroll
                for (int i = 0; i < 4; ++i) {
                    int p = (i * 2 + kh) * 33 + l15 * 2 + kw;
                    af[i] = __builtin_bit_cast(short8,
                        *(const uint4*)(As + p * 128 + h * 64 +
                                        (((sl ^ (p >> 1)) & 7) << 3)));
                }
#pragma unroll
                for (int j = 0; j < 4; ++j)
                    bf[j] = __builtin_bit_cast(short8,
                        *(const uint4*)(wtB +
                            ((size_t)((tap * 16 + h * 8 + sl) * 256) +
                             wn + j * 16 + l15) * 8));
#pragma unroll
                for (int i = 0; i < 4; ++i)
#pragma unroll
                    for (int j = 0; j < 4; ++j)
                        acc[i][j] = __builtin_amdgcn_mfma_f32_16x16x32_bf16(
                            af[i], bf[j], acc[i][j], 0, 0, 0);
            }
        }
    }

    // fused pool: bias+ReLU, sum over the block's 64 spatial positions
    float s4[4];
#pragma unroll
    for (int j = 0; j < 4; ++j) {
        float bv = bias[wn + j * 16 + l15];
        float s = 0.f;
#pragma unroll
        for (int i = 0; i < 4; ++i)
#pragma unroll
            for (int r = 0; r < 4; ++r)
                s += fmaxf(acc[i][j][r] + bv, 0.f);
        s += __shfl_xor(s, 16, 64);   // reduce across quads (same n)
        s += __shfl_xor(s, 32, 64);
        s4[j] = s;
    }
    __syncthreads();   // all K-loop LDS reads done before sred alias write
    if (quad == 0) {
#pragma unroll
        for (int j = 0; j < 4; ++j) sred[wn + j * 16 + l15] = s4[j];
    }
    __syncthreads();
    atomicAdd(v + (size_t)bimg * 256 + tid, sred[tid] * (1.f / 256.f));
}

// ---------------------------------------------------------------------------
// Tail: one block (256 thr) per sample; K-split GEMV stages, float4 weights.
// ---------------------------------------------------------------------------
template<int N, int K, int S, bool RELU>
__device__ __forceinline__ void gemv_stage(const float* __restrict__ w,
                                           const float* __restrict__ bias,
                                           const float* in, float* outv,
                                           float4* red4, int tid) {
    constexpr int G = N / 4;
    constexpr int CHK = K / S;
    static_assert(G * S == 256 && CHK * S == K, "stage shape");
    const int g = tid % G, s = tid / G;
    const float4* wp = (const float4*)w;
    float4 a; a.x = a.y = a.z = a.w = 0.f;
    const int k0 = s * CHK;
#pragma unroll 8
    for (int i = 0; i < CHK; ++i) {
        float x = in[k0 + i];
        float4 wv = wp[(size_t)(k0 + i) * G + g];
        a.x = fmaf(x, wv.x, a.x);
        a.y = fmaf(x, wv.y, a.y);
        a.z = fmaf(x, wv.z, a.z);
        a.w = fmaf(x, wv.w, a.w);
    }
    red4[tid] = a;
    __syncthreads();
    if (tid < N) {
        int gg = tid >> 2, e = tid & 3;
        float vv = bias[tid];
#pragma unroll
        for (int ss = 0; ss < S; ++ss) {
            const float* rp = (const float*)(red4 + ss * G + gg);
            vv += rp[e];
        }
        if (RELU) vv = fmaxf(vv, 0.f);
        outv[tid] = vv;
    }
    __syncthreads();
}

__global__ __launch_bounds__(256) void tail_kernel(
    const float* __restrict__ prop, const int* __restrict__ task_ids,
    const float* __restrict__ p1_w, const float* __restrict__ p1_b,
    const float* __restrict__ p2_w, const float* __restrict__ p2_b,
    const float* __restrict__ v,
    const float* __restrict__ f1_w, const float* __restrict__ f1_b,
    const float* __restrict__ f2_w, const float* __restrict__ f2_b,
    const float* __restrict__ task_emb,
    const float* __restrict__ g_w, const float* __restrict__ g_b,
    const float* __restrict__ h1_w, const float* __restrict__ h1_b,
    const float* __restrict__ h2_w, const float* __restrict__ h2_b,
    const float* __restrict__ h3_w, const float* __restrict__ h3_b,
    float* __restrict__ out) {
    const int b   = blockIdx.x;
    const int tid = threadIdx.x;
    const int t   = task_ids[b];
    __shared__ float sa[320];
    __shared__ float sb[288];
    __shared__ float sph[64];
    __shared__ float4 red4[256];

    sa[tid] = (tid < 256) ? v[(size_t)b * 256 + tid] : 0.f;
    if (tid < 64) {
        float h = p1_b[tid];
#pragma unroll
        for (int k = 0; k < 7; ++k) h = fmaf(prop[b * 7 + k], p1_w[k * 64 + tid], h);
        sph[tid] = fmaxf(h, 0.f);
    }
    __syncthreads();
    gemv_stage<64, 64, 16, false>(p2_w, p2_b, sph, sa + 256, red4, tid);
    gemv_stage<256, 320, 4, true>(f1_w, f1_b, sa, sb, red4, tid);
    gemv_stage<256, 256, 4, true>(f2_w, f2_b, sb, sa, red4, tid);
    if (tid < 32) sa[256 + tid] = task_emb[t * 32 + tid];
    __syncthreads();
    gemv_stage<256, 288, 4, true>(g_w, g_b, sa, sb, red4, tid);
    gemv_stage<128, 256, 8, true>(h1_w + (size_t)t * 32768, h1_b + t * 128,
                                  sb, sa, red4, tid);
    gemv_stage<128, 128, 8, true>(h2_w + (size_t)t * 16384, h2_b + t * 128,
                                  sa, sb, red4, tid);
    if (tid < 128) {
        float4 wv = ((const float4*)(h3_w + (size_t)t * 512))[tid];
        float x = sb[tid];
        float r0 = x * wv.x, r1 = x * wv.y, r2 = x * wv.z, r3 = x * wv.w;
#pragma unroll
        for (int off = 1; off < 64; off <<= 1) {
            r0 += __shfl_xor(r0, off, 64);
            r1 += __shfl_xor(r1, off, 64);
            r2 += __shfl_xor(r2, off, 64);
            r3 += __shfl_xor(r3, off, 64);
        }
        if ((tid & 63) == 0) {
            float4 rv; rv.x = r0; rv.y = r1; rv.z = r2; rv.w = r3;
            red4[tid >> 6] = rv;
        }
    }
    __syncthreads();
    if (tid < 4) {
        const float* ra = (const float*)(red4 + 0);
        const float* rb = (const float*)(red4 + 1);
        out[b * 4 + tid] = ra[tid] + rb[tid] + h3_b[t * 4 + tid];
    }
}

// ---------------------------------------------------------------------------
extern "C" void kernel_launch(void* const* d_in, const int* in_sizes, int n_in,
                              void* d_out, int out_size, void* d_ws, size_t ws_size,
                              hipStream_t stream) {
    (void)in_sizes; (void)n_in; (void)out_size;
    const float* images   = (const float*)d_in[0];
    const float* prop     = (const float*)d_in[1];
    const int*   task_ids = (const int*)d_in[2];
    const float* c1_w = (const float*)d_in[3];
    const float* c1_b = (const float*)d_in[4];
    const float* c2_w = (const float*)d_in[5];
    const float* c2_b = (const float*)d_in[6];
    const float* c3_w = (const float*)d_in[7];
    const float* c3_b = (const float*)d_in[8];
    const float* p1_w = (const float*)d_in[9];
    const float* p1_b = (const float*)d_in[10];
    const float* p2_w = (const float*)d_in[11];
    const float* p2_b = (const float*)d_in[12];
    const float* f1_w = (const float*)d_in[13];
    const float* f1_b = (const float*)d_in[14];
    const float* f2_w = (const float*)d_in[15];
    const float* f2_b = (const float*)d_in[16];
    const float* temb = (const float*)d_in[17];
    const float* g_w  = (const float*)d_in[18];
    const float* g_b  = (const float*)d_in[19];
    const float* h1_w = (const float*)d_in[20];
    const float* h1_b = (const float*)d_in[21];
    const float* h2_w = (const float*)d_in[22];
    const float* h2_b = (const float*)d_in[23];
    const float* h3_w = (const float*)d_in[24];
    const float* h3_b = (const float*)d_in[25];
    float* out = (float*)d_out;

    const size_t per_img = (size_t)65 * 65 * 64 * 2 + (size_t)33 * 33 * 128 * 2;
    const size_t fixed   = (size_t)256 * 256 * 4 + 1728 * 4 +
                           (size_t)73728 * 2 + (size_t)294912 * 2 + 4096;
    int CHI = 64;
    if (ws_size >= fixed + per_img * 256) CHI = 256;
    else if (ws_size >= fixed + per_img * 128) CHI = 128;

    char* ws = (char*)d_ws;
    size_t off = 0;
    auto alloc = [&](size_t bytes) {
        void* p = ws + off;
        off += (bytes + 255) & ~(size_t)255;
        return p;
    };
    __hip_bfloat16* act1 = (__hip_bfloat16*)alloc((size_t)CHI * 65 * 65 * 64 * 2);
    __hip_bfloat16* act2 = (__hip_bfloat16*)alloc((size_t)CHI * 33 * 33 * 128 * 2);
    float*          vbuf = (float*)alloc((size_t)256 * 256 * 4);
    __hip_bfloat16* w1b  = (__hip_bfloat16*)alloc((size_t)2048 * 2);
    __hip_bfloat16* w2t  = (__hip_bfloat16*)alloc((size_t)73728 * 2);
    __hip_bfloat16* w3t  = (__hip_bfloat16*)alloc((size_t)294912 * 2);

    prep_kernel<<<dim3(CHI + 8 + 288 + 1152), 256, 0, stream>>>(
        (uint4*)act1, (uint4*)act2, (float4*)vbuf, CHI,
        c1_w, w1b, c2_w, w2t, c3_w, w3t);

    for (int c0 = 0; c0 < 256; c0 += CHI) {
        const float* img_c = images + (size_t)c0 * 3 * 128 * 128;
        conv1_mfma_kernel<<<dim3(16, CHI), dim3(256), 0, stream>>>(
            img_c, w1b, c1_b, act1);
        conv2_gemm_kernel<<<dim3(CHI * 16), 256, 0, stream>>>(
            act1, w2t, c2_b, act2);
        conv3_gemm_pool_kernel<<<dim3(CHI * 4), 256, 0, stream>>>(
            act2, w3t, c3_b, vbuf + (size_t)c0 * 256);
    }
    tail_kernel<<<256, 256, 0, stream>>>(prop, task_ids, p1_w, p1_b, p2_w, p2_b,
                                         vbuf, f1_w, f1_b, f2_w, f2_b, temb,
                                         g_w, g_b, h1_w, h1_b, h2_w, h2_b,
                                         h3_w, h3_b, out);
}

// Round 13
// 324.702 us; speedup vs baseline: 1.0181x; 1.0181x over previous
//
#include <hip/hip_runtime.h>
#include <hip/hip_bf16.h>

#define DIV_UP(a,b) (((a)+(b)-1)/(b))

typedef __attribute__((ext_vector_type(8))) short short8;
typedef __attribute__((ext_vector_type(4))) float f32x4;

__device__ __forceinline__ ushort bf16_bits(float x) {
    return __builtin_bit_cast(ushort, __float2bfloat16(x));
}

// async global->LDS 16B DMA: LDS dest is wave-uniform base + lane*16,
// global src is per-lane (pre-swizzled source pattern, guide rule 21)
__device__ __forceinline__ void gload_lds16(const ushort* g, ushort* l) {
    __builtin_amdgcn_global_load_lds(
        (const __attribute__((address_space(1))) void*)g,
        (__attribute__((address_space(3))) void*)l, 16, 0, 0);
}

// ---------------------------------------------------------------------------
// Merged prep: halo-zero (act1/act2/vbuf) + all three weight repacks in ONE
// launch, partitioned by blockIdx range (saves 3 serial launch overheads).
// grid = CHI + 8 + 288 + 1152 blocks of 256 threads.
// ---------------------------------------------------------------------------
__global__ __launch_bounds__(256) void prep_kernel(
    uint4* __restrict__ act1, uint4* __restrict__ act2,
    float4* __restrict__ vbuf, int CHI,
    const float* __restrict__ c1_w, __hip_bfloat16* __restrict__ w1b,
    const float* __restrict__ c2_w, __hip_bfloat16* __restrict__ w2t,
    const float* __restrict__ c3_w, __hip_bfloat16* __restrict__ w3t) {
    const int tid = threadIdx.x;
    int bx = blockIdx.x;

    if (bx < CHI) {                       // ---- halo zero for image bx ----
        const int b = bx;
        const uint4 z = {0u, 0u, 0u, 0u};
        uint4* a1 = act1 + (size_t)b * 33800;     // 65*65*64 bf16
        for (int i = tid; i < 520; i += 256) a1[i] = z;
        for (int i = tid; i < 512; i += 256) {
            int r = (i >> 3) + 1;
            a1[r * 520 + (i & 7)] = z;
        }
        uint4* a2 = act2 + (size_t)b * 17424;     // 33*33*128 bf16
        for (int i = tid; i < 528; i += 256) a2[i] = z;
        for (int i = tid; i < 512; i += 256) {
            int r = (i >> 4) + 1;
            a2[r * 528 + (i & 15)] = z;
        }
        int idx = b * 256 + tid;
        float4 zf = {0.f, 0.f, 0.f, 0.f};
        if (idx < 16384) vbuf[idx] = zf;
        return;
    }
    bx -= CHI;

    if (bx < 8) {                         // ---- conv1 weights [64][32] ----
        int t = bx * 256 + tid;           // t < 2048
        int k  = t & 31;
        int oc = t >> 5;
        w1b[t] = (k < 27) ? __float2bfloat16(c1_w[oc * 27 + k])
                          : __float2bfloat16(0.f);
        return;
    }
    bx -= 8;

    const float* src;
    __hip_bfloat16* dst;
    int O, C, t;
    if (bx < 288) {                       // ---- conv2 weights repack ----
        src = c2_w; dst = w2t; O = 128; C = 64;
        t = bx * 256 + tid;               // t < 73728
    } else {                              // ---- conv3 weights repack ----
        src = c3_w; dst = w3t; O = 256; C = 128;
        t = (bx - 288) * 256 + tid;       // t < 294912
    }
    int e   = t & 7;
    int r   = t >> 3;
    int n   = r % O;
    int q   = r / O;
    int SEG = C >> 3;
    int sg  = q % SEG;
    int tap = q / SEG;
    dst[t] = __float2bfloat16(src[(n * C + sg * 8 + e) * 9 + tap]);
}

// ---------------------------------------------------------------------------
// conv1 as MFMA implicit-GEMM (round-4 proven version):
// async-DMA input stage -> reg im2col -> swizzled Al -> MFMA -> direct stores
// ---------------------------------------------------------------------------
__global__ __launch_bounds__(256) void conv1_mfma_kernel(
    const float* __restrict__ in,
    const __hip_bfloat16* __restrict__ wB,   // [64][32] bf16
    const float* __restrict__ bias,
    __hip_bfloat16* __restrict__ out) {
    const int tid  = threadIdx.x;
    const int lane = tid & 63;
    const int wv   = tid >> 6;
    const int l15  = lane & 15;
    const int quad = lane >> 4;
    const int tile = blockIdx.x;             // 0..15, 4 oh rows each
    const int b    = blockIdx.y;
    const int oh0  = tile << 2;

    __shared__ __align__(16) char smem[30208];
    float*  sx = (float*)smem;               // [27][128] fp32, row q = c*9+r
    ushort* Al = (ushort*)(smem + 13824);    // [256][32] bf16 swizzled, 16 KB

    const float* ip  = in + (size_t)b * 3 * 128 * 128;
    const int    ih0 = 2 * oh0 - 1;

    // stage 27 rows x 128 fp32 = 864 16B chunks, linear LDS dest
#pragma unroll
    for (int it = 0; it < 4; ++it) {
        int e = (it << 8) + tid;
        if (e < 864) {
            int q = e >> 5, k = e & 31;      // row q, chunk k
            int c = q / 9, r = q - c * 9;
            int row = ih0 + r;
            if (row < 0) row = 0;            // clamp; masked in im2col
            gload_lds16((const ushort*)(ip + c * 16384 + row * 128 + k * 4),
                        (ushort*)smem + (size_t)e * 8);
        }
    }
    __syncthreads();   // drains vmcnt -> input resident in LDS

    // reg im2col: thread owns px = tid; 27 taps from sx with edge masks
    const int px = tid, ohl = px >> 6, ow = px & 63;
    union { uint4 u4[4]; ushort us[32]; } rowv;
#pragma unroll
    for (int c = 0; c < 3; ++c)
#pragma unroll
        for (int kh = 0; kh < 3; ++kh) {
            const bool rok = (ih0 + 2 * ohl + kh) >= 0;
            const float* srow = sx + (c * 9 + 2 * ohl + kh) * 128;
#pragma unroll
            for (int kw = 0; kw < 3; ++kw) {
                int iw = 2 * ow + kw - 1;
                bool ok = rok && (iw >= 0);
                float x = srow[iw < 0 ? 0 : iw];
                rowv.us[c * 9 + kh * 3 + kw] = bf16_bits(ok ? x : 0.f);
            }
        }
#pragma unroll
    for (int k = 27; k < 32; ++k) rowv.us[k] = 0;
#pragma unroll
    for (int q = 0; q < 4; ++q)
        *(uint4*)(Al + px * 32 + (((q ^ (px >> 1)) & 3) << 3)) = rowv.u4[q];

    // weight fragment (4 KB table, L2-hot): af rows = oc
    short8 af[4], bf[4];
#pragma unroll
    for (int i = 0; i < 4; ++i)
        af[i] = __builtin_bit_cast(short8,
            *(const uint4*)(wB + ((i * 16 + l15) * 32 + quad * 8)));

    __syncthreads();   // Al visible (exchange itself is intra-wave)

#pragma unroll
    for (int j = 0; j < 4; ++j) {
        int p = wv * 64 + j * 16 + l15;
        bf[j] = __builtin_bit_cast(short8,
            *(const uint4*)(Al + p * 32 + (((quad ^ (p >> 1)) & 3) << 3)));
    }
    f32x4 acc[4][4];
#pragma unroll
    for (int i = 0; i < 4; ++i)
#pragma unroll
        for (int j = 0; j < 4; ++j)
            acc[i][j] = __builtin_amdgcn_mfma_f32_16x16x32_bf16(
                af[i], bf[j], (f32x4){0.f, 0.f, 0.f, 0.f}, 0, 0, 0);

    float4 bv[4];
#pragma unroll
    for (int i = 0; i < 4; ++i)
        bv[i] = *(const float4*)(bias + i * 16 + quad * 4);

    // direct stores: D frag (col=px=j*16+l15 wave-local, row=oc=i*16+quad*4+r)
    __hip_bfloat16* ob = out + (((size_t)b * 65 + oh0 + 1) * 65 + 1) * 64;
#pragma unroll
    for (int j = 0; j < 4; ++j) {
        const int oww = j * 16 + l15;
        __hip_bfloat16* op = ob + ((size_t)(wv * 65) + oww) * 64 + quad * 4;
#pragma unroll
        for (int i = 0; i < 4; ++i) {
            union { uint2 u2; ushort us[4]; } pk;
#pragma unroll
            for (int r = 0; r < 4; ++r)
                pk.us[r] = bf16_bits(
                    fmaxf(acc[i][j][r] + ((const float*)&bv[i])[r], 0.f));
            *(uint2*)(op + i * 16) = pk.u2;
        }
    }
}

// ---------------------------------------------------------------------------
// conv2 implicit-GEMM, small-tile/high-occupancy v2 (round-8/9/11 proven
// BEST — 66us): M-tile = 64 px (2 oh x 32 ow), N = 128 oc; wave = 32 px x
// 64 oc. Full-3-bit XOR chunk swizzle -> af reads 2-way bank aliasing
// (free). LDS 5x65 px x 128B = 41600 B -> 3 blocks/CU (measured optimum:
// 2blk=83us, 3blk=66us, 6blk=74us). LDS epilogue IS the store-coalescing
// stage (direct frag stores measured 10us slower, R12).
// ---------------------------------------------------------------------------
__global__ __launch_bounds__(256, 3) void conv2_gemm_kernel(
    const __hip_bfloat16* __restrict__ act,
    const __hip_bfloat16* __restrict__ wtB,   // [tap][8][128][8]
    const float* __restrict__ bias,
    __hip_bfloat16* __restrict__ out) {
    const int tid  = threadIdx.x;
    const int lane = tid & 63;
    const int w    = tid >> 6;
    const int l15  = lane & 15;
    const int quad = lane >> 4;
    const int per  = gridDim.x >> 3;
    const int Mt   = (blockIdx.x & 7) * per + (blockIdx.x >> 3);
    const int bimg = Mt >> 4;
    const int oh0  = (Mt & 15) << 1;         // 2 output rows per tile

    __shared__ __align__(16) char smem[41600];   // 325 px * 128 B
    ushort* As = (ushort*)smem;
    ushort* Cs = (ushort*)smem;                  // epilogue alias (16.9 KB)

    f32x4 acc[2][4];
#pragma unroll
    for (int i = 0; i < 2; ++i)
#pragma unroll
        for (int j = 0; j < 4; ++j) acc[i][j] = (f32x4){0.f, 0.f, 0.f, 0.f};

    const int pxw = (w >> 1) << 5;           // wave owns 32 px
    const int wn  = (w & 1) << 6;            // wave owns 64 oc
    const size_t abase = ((size_t)(bimg * 65 + 2 * oh0)) * 65 * 64;
    const ushort* ap = (const ushort*)act;

    // stage 5 rows x 65 px x 64 ch = 2600 16B chunks, full lines.
    // dest chunk t of pixel p holds source chunk t^((p>>1)&7) (ch = 8*q)
#pragma unroll
    for (int it = 0; it < 11; ++it) {
        int c = (it << 8) + tid;
        if (c < 2600) {
            int p = c >> 3, t = c & 7;       // p = r*65 + px
            int q = t ^ ((p >> 1) & 7);
            gload_lds16(ap + abase + (size_t)p * 64 + q * 8,
                        As + (size_t)c * 8);
        }
    }
    __syncthreads();   // drains vmcnt -> tile resident in LDS

    for (int h = 0; h < 2; ++h) {
        const int q = h * 4 + quad;          // logical K-seg (8 ch each)
#pragma unroll
        for (int tap = 0; tap < 9; ++tap) {
            const int kh = tap / 3, kw = tap - kh * 3;
            short8 af[2], bf[4];
#pragma unroll
            for (int i = 0; i < 2; ++i) {    // A = pixels (32 per wave)
                int ml = pxw + i * 16 + l15;
                int p  = ((ml >> 5) * 2 + kh) * 65 + ((ml & 31) * 2 + kw);
                af[i] = __builtin_bit_cast(short8,
                    *(const uint4*)(As + p * 64 +
                                    ((q ^ ((p >> 1) & 7)) << 3)));
            }
#pragma unroll
            for (int j = 0; j < 4; ++j)      // B = weights (64 oc per wave)
                bf[j] = __builtin_bit_cast(short8,
                    *(const uint4*)(wtB +
                        ((size_t)((tap * 8 + h * 4 + quad) * 128) +
                         wn + j * 16 + l15) * 8));
#pragma unroll
            for (int i = 0; i < 2; ++i)
#pragma unroll
                for (int j = 0; j < 4; ++j)
                    acc[i][j] = __builtin_amdgcn_mfma_f32_16x16x32_bf16(
                        af[i], bf[j], acc[i][j], 0, 0, 0);
        }
    }

    // epilogue: bias+ReLU -> bf16 tile in LDS -> coalesced 8B stores
    __syncthreads();
#pragma unroll
    for (int j = 0; j < 4; ++j) {
        int n = wn + j * 16 + l15;
        float bv = bias[n];
#pragma unroll
        for (int i = 0; i < 2; ++i)
#pragma unroll
            for (int r = 0; r < 4; ++r) {
                int ml = pxw + i * 16 + quad * 4 + r;   // px 0..63
                Cs[ml * 132 + n] = bf16_bits(fmaxf(acc[i][j][r] + bv, 0.f));
            }
    }
    __syncthreads();
#pragma unroll
    for (int q2 = 0; q2 < 8; ++q2) {
        int c   = tid + 256 * q2;
        int row = c >> 5;
        int off = c & 31;
        uint2 val = *(const uint2*)(Cs + row * 132 + off * 4);
        int m  = (Mt << 6) + row;
        int b  = m >> 10;
        int rr = m & 1023;
        int oh = rr >> 5;
        int ow = rr & 31;
        size_t pix = ((size_t)(b * 33 + oh + 1) * 33 + (ow + 1));
        *(uint2*)(out + pix * 128 + off * 4) = val;
    }
}

// ---------------------------------------------------------------------------
// conv3 implicit-GEMM + fused pool (round-4 proven version): full 128-ch
// A-tile staged ONCE via async global_load_lds (full 256B lines, linear
// dest, inverse-swizzled source), single barrier. Tap loop NOT unrolled.
// M-tile 64 px (4 oh x 16 ow), N = 256. LDS 304 px * 256 B = 77824 B.
// ---------------------------------------------------------------------------
__global__ __launch_bounds__(256, 2) void conv3_gemm_pool_kernel(
    const __hip_bfloat16* __restrict__ act,
    const __hip_bfloat16* __restrict__ wtB,   // [tap][16][256][8]
    const float* __restrict__ bias,
    float* __restrict__ v /* [CHI,256], pre-zeroed */) {
    const int tid  = threadIdx.x;
    const int lane = tid & 63;
    const int w    = tid >> 6;
    const int l15  = lane & 15;
    const int quad = lane >> 4;
    const int per  = gridDim.x >> 3;
    const int Mt   = (blockIdx.x & 7) * per + (blockIdx.x >> 3);
    const int bimg = Mt >> 2;
    const int oh0  = (Mt & 3) << 2;

    __shared__ __align__(16) char smem[77824];
    ushort* As   = (ushort*)smem;
    float*  sred = (float*)smem;                 // pool alias (1 KB)

    f32x4 acc[4][4];
#pragma unroll
    for (int i = 0; i < 4; ++i)
#pragma unroll
        for (int j = 0; j < 4; ++j) acc[i][j] = (f32x4){0.f, 0.f, 0.f, 0.f};

    const int wn = w << 6;                       // wave owns 64 n-cols
    const size_t abase = ((size_t)(bimg * 33 + 2 * oh0)) * 33 * 128;
    const ushort* ap = (const ushort*)act;

    // stage 297 px x 128 ch (9 rows x 33 px), 16 chunks/px, 4864 chunks total.
#pragma unroll
    for (int it = 0; it < 19; ++it) {
        int c  = (it << 8) + tid;
        int p  = c >> 4;                 // pixel
        int t  = c & 15;                 // dest chunk-in-px
        int h  = t >> 3;                 // 64-ch half
        int ss = (t & 7) ^ ((p >> 1) & 7);
        gload_lds16(ap + abase + (size_t)p * 128 + h * 64 + ss * 8,
                    As + (size_t)c * 8);
    }
    __syncthreads();   // drains vmcnt -> all of A resident in LDS

    for (int h = 0; h < 2; ++h) {
#pragma unroll 1
        for (int tap = 0; tap < 9; ++tap) {
            const int kh = tap / 3, kw = tap - kh * 3;
#pragma unroll
            for (int ks = 0; ks < 2; ++ks) {
                short8 af[4], bf[4];
                const int sl = ks * 4 + quad;        // seg within 64-ch half
#pragma unroll
                for (int i = 0; i < 4; ++i) {
                    int p = (i * 2 + kh) * 33 + l15 * 2 + kw;
                    af[i] = __builtin_bit_cast(short8,
                        *(const uint4*)(As + p * 128 + h * 64 +
                                        (((sl ^ (p >> 1)) & 7) << 3)));
                }
#pragma unroll
                for (int j = 0; j < 4; ++j)
                    bf[j] = __builtin_bit_cast(short8,
                        *(const uint4*)(wtB +
                            ((size_t)((tap * 16 + h * 8 + sl) * 256) +
                             wn + j * 16 + l15) * 8));
#pragma unroll
                for (int i = 0; i < 4; ++i)
#pragma unroll
                    for (int j = 0; j < 4; ++j)
                        acc[i][j] = __builtin_amdgcn_mfma_f32_16x16x32_bf16(
                            af[i], bf[j], acc[i][j], 0, 0, 0);
            }
        }
    }

    // fused pool: bias+ReLU, sum over the block's 64 spatial positions
    float s4[4];
#pragma unroll
    for (int j = 0; j < 4; ++j) {
        float bv = bias[wn + j * 16 + l15];
        float s = 0.f;
#pragma unroll
        for (int i = 0; i < 4; ++i)
#pragma unroll
            for (int r = 0; r < 4; ++r)
                s += fmaxf(acc[i][j][r] + bv, 0.f);
        s += __shfl_xor(s, 16, 64);   // reduce across quads (same n)
        s += __shfl_xor(s, 32, 64);
        s4[j] = s;
    }
    __syncthreads();   // all K-loop LDS reads done before sred alias write
    if (quad == 0) {
#pragma unroll
        for (int j = 0; j < 4; ++j) sred[wn + j * 16 + l15] = s4[j];
    }
    __syncthreads();
    atomicAdd(v + (size_t)bimg * 256 + tid, sred[tid] * (1.f / 256.f));
}

// ---------------------------------------------------------------------------
// Tail: one block (256 thr) per sample; K-split GEMV stages, float4 weights.
// ---------------------------------------------------------------------------
template<int N, int K, int S, bool RELU>
__device__ __forceinline__ void gemv_stage(const float* __restrict__ w,
                                           const float* __restrict__ bias,
                                           const float* in, float* outv,
                                           float4* red4, int tid) {
    constexpr int G = N / 4;
    constexpr int CHK = K / S;
    static_assert(G * S == 256 && CHK * S == K, "stage shape");
    const int g = tid % G, s = tid / G;
    const float4* wp = (const float4*)w;
    float4 a; a.x = a.y = a.z = a.w = 0.f;
    const int k0 = s * CHK;
#pragma unroll 8
    for (int i = 0; i < CHK; ++i) {
        float x = in[k0 + i];
        float4 wv = wp[(size_t)(k0 + i) * G + g];
        a.x = fmaf(x, wv.x, a.x);
        a.y = fmaf(x, wv.y, a.y);
        a.z = fmaf(x, wv.z, a.z);
        a.w = fmaf(x, wv.w, a.w);
    }
    red4[tid] = a;
    __syncthreads();
    if (tid < N) {
        int gg = tid >> 2, e = tid & 3;
        float vv = bias[tid];
#pragma unroll
        for (int ss = 0; ss < S; ++ss) {
            const float* rp = (const float*)(red4 + ss * G + gg);
            vv += rp[e];
        }
        if (RELU) vv = fmaxf(vv, 0.f);
        outv[tid] = vv;
    }
    __syncthreads();
}

__global__ __launch_bounds__(256) void tail_kernel(
    const float* __restrict__ prop, const int* __restrict__ task_ids,
    const float* __restrict__ p1_w, const float* __restrict__ p1_b,
    const float* __restrict__ p2_w, const float* __restrict__ p2_b,
    const float* __restrict__ v,
    const float* __restrict__ f1_w, const float* __restrict__ f1_b,
    const float* __restrict__ f2_w, const float* __restrict__ f2_b,
    const float* __restrict__ task_emb,
    const float* __restrict__ g_w, const float* __restrict__ g_b,
    const float* __restrict__ h1_w, const float* __restrict__ h1_b,
    const float* __restrict__ h2_w, const float* __restrict__ h2_b,
    const float* __restrict__ h3_w, const float* __restrict__ h3_b,
    float* __restrict__ out) {
    const int b   = blockIdx.x;
    const int tid = threadIdx.x;
    const int t   = task_ids[b];
    __shared__ float sa[320];
    __shared__ float sb[288];
    __shared__ float sph[64];
    __shared__ float4 red4[256];

    sa[tid] = (tid < 256) ? v[(size_t)b * 256 + tid] : 0.f;
    if (tid < 64) {
        float h = p1_b[tid];
#pragma unroll
        for (int k = 0; k < 7; ++k) h = fmaf(prop[b * 7 + k], p1_w[k * 64 + tid], h);
        sph[tid] = fmaxf(h, 0.f);
    }
    __syncthreads();
    gemv_stage<64, 64, 16, false>(p2_w, p2_b, sph, sa + 256, red4, tid);
    gemv_stage<256, 320, 4, true>(f1_w, f1_b, sa, sb, red4, tid);
    gemv_stage<256, 256, 4, true>(f2_w, f2_b, sb, sa, red4, tid);
    if (tid < 32) sa[256 + tid] = task_emb[t * 32 + tid];
    __syncthreads();
    gemv_stage<256, 288, 4, true>(g_w, g_b, sa, sb, red4, tid);
    gemv_stage<128, 256, 8, true>(h1_w + (size_t)t * 32768, h1_b + t * 128,
                                  sb, sa, red4, tid);
    gemv_stage<128, 128, 8, true>(h2_w + (size_t)t * 16384, h2_b + t * 128,
                                  sa, sb, red4, tid);
    if (tid < 128) {
        float4 wv = ((const float4*)(h3_w + (size_t)t * 512))[tid];
        float x = sb[tid];
        float r0 = x * wv.x, r1 = x * wv.y, r2 = x * wv.z, r3 = x * wv.w;
#pragma unroll
        for (int off = 1; off < 64; off <<= 1) {
            r0 += __shfl_xor(r0, off, 64);
            r1 += __shfl_xor(r1, off, 64);
            r2 += __shfl_xor(r2, off, 64);
            r3 += __shfl_xor(r3, off, 64);
        }
        if ((tid & 63) == 0) {
            float4 rv; rv.x = r0; rv.y = r1; rv.z = r2; rv.w = r3;
            red4[tid >> 6] = rv;
        }
    }
    __syncthreads();
    if (tid < 4) {
        const float* ra = (const float*)(red4 + 0);
        const float* rb = (const float*)(red4 + 1);
        out[b * 4 + tid] = ra[tid] + rb[tid] + h3_b[t * 4 + tid];
    }
}

// ---------------------------------------------------------------------------
extern "C" void kernel_launch(void* const* d_in, const int* in_sizes, int n_in,
                              void* d_out, int out_size, void* d_ws, size_t ws_size,
                              hipStream_t stream) {
    (void)in_sizes; (void)n_in; (void)out_size;
    const float* images   = (const float*)d_in[0];
    const float* prop     = (const float*)d_in[1];
    const int*   task_ids = (const int*)d_in[2];
    const float* c1_w = (const float*)d_in[3];
    const float* c1_b = (const float*)d_in[4];
    const float* c2_w = (const float*)d_in[5];
    const float* c2_b = (const float*)d_in[6];
    const float* c3_w = (const float*)d_in[7];
    const float* c3_b = (const float*)d_in[8];
    const float* p1_w = (const float*)d_in[9];
    const float* p1_b = (const float*)d_in[10];
    const float* p2_w = (const float*)d_in[11];
    const float* p2_b = (const float*)d_in[12];
    const float* f1_w = (const float*)d_in[13];
    const float* f1_b = (const float*)d_in[14];
    const float* f2_w = (const float*)d_in[15];
    const float* f2_b = (const float*)d_in[16];
    const float* temb = (const float*)d_in[17];
    const float* g_w  = (const float*)d_in[18];
    const float* g_b  = (const float*)d_in[19];
    const float* h1_w = (const float*)d_in[20];
    const float* h1_b = (const float*)d_in[21];
    const float* h2_w = (const float*)d_in[22];
    const float* h2_b = (const float*)d_in[23];
    const float* h3_w = (const float*)d_in[24];
    const float* h3_b = (const float*)d_in[25];
    float* out = (float*)d_out;

    const size_t per_img = (size_t)65 * 65 * 64 * 2 + (size_t)33 * 33 * 128 * 2;
    const size_t fixed   = (size_t)256 * 256 * 4 + 1728 * 4 +
                           (size_t)73728 * 2 + (size_t)294912 * 2 + 4096;
    int CHI = 64;
    if (ws_size >= fixed + per_img * 256) CHI = 256;
    else if (ws_size >= fixed + per_img * 128) CHI = 128;

    char* ws = (char*)d_ws;
    size_t off = 0;
    auto alloc = [&](size_t bytes) {
        void* p = ws + off;
        off += (bytes + 255) & ~(size_t)255;
        return p;
    };
    __hip_bfloat16* act1 = (__hip_bfloat16*)alloc((size_t)CHI * 65 * 65 * 64 * 2);
    __hip_bfloat16* act2 = (__hip_bfloat16*)alloc((size_t)CHI * 33 * 33 * 128 * 2);
    float*          vbuf = (float*)alloc((size_t)256 * 256 * 4);
    __hip_bfloat16* w1b  = (__hip_bfloat16*)alloc((size_t)2048 * 2);
    __hip_bfloat16* w2t  = (__hip_bfloat16*)alloc((size_t)73728 * 2);
    __hip_bfloat16* w3t  = (__hip_bfloat16*)alloc((size_t)294912 * 2);

    prep_kernel<<<dim3(CHI + 8 + 288 + 1152), 256, 0, stream>>>(
        (uint4*)act1, (uint4*)act2, (float4*)vbuf, CHI,
        c1_w, w1b, c2_w, w2t, c3_w, w3t);

    for (int c0 = 0; c0 < 256; c0 += CHI) {
        const float* img_c = images + (size_t)c0 * 3 * 128 * 128;
        conv1_mfma_kernel<<<dim3(16, CHI), dim3(256), 0, stream>>>(
            img_c, w1b, c1_b, act1);
        conv2_gemm_kernel<<<dim3(CHI * 16), 256, 0, stream>>>(
            act1, w2t, c2_b, act2);
        conv3_gemm_pool_kernel<<<dim3(CHI * 4), 256, 0, stream>>>(
            act2, w3t, c3_b, vbuf + (size_t)c0 * 256);
    }
    tail_kernel<<<256, 256, 0, stream>>>(prop, task_ids, p1_w, p1_b, p2_w, p2_b,
                                         vbuf, f1_w, f1_b, f2_w, f2_b, temb,
                                         g_w, g_b, h1_w, h1_b, h2_w, h2_b,
                                         h3_w, h3_b, out);
}

// Round 15
// 303.219 us; speedup vs baseline: 1.0902x; 1.0708x over previous
//
#include <hip/hip_runtime.h>
#include <hip/hip_bf16.h>

#define DIV_UP(a,b) (((a)+(b)-1)/(b))

typedef __attribute__((ext_vector_type(8))) short short8;
typedef __attribute__((ext_vector_type(4))) float f32x4;

__device__ __forceinline__ ushort bf16_bits(float x) {
    return __builtin_bit_cast(ushort, __float2bfloat16(x));
}

// async global->LDS 16B DMA: LDS dest is wave-uniform base + lane*16,
// global src is per-lane (pre-swizzled source pattern, guide rule 21)
__device__ __forceinline__ void gload_lds16(const ushort* g, ushort* l) {
    __builtin_amdgcn_global_load_lds(
        (const __attribute__((address_space(1))) void*)g,
        (__attribute__((address_space(3))) void*)l, 16, 0, 0);
}

// ---------------------------------------------------------------------------
// Merged prep: halo-zero (act2/vbuf; act1 no longer exists) + weight repacks.
// grid = CHI + 8 + 288 + 1152 blocks of 256 threads.
// ---------------------------------------------------------------------------
__global__ __launch_bounds__(256) void prep_kernel(
    uint4* __restrict__ act2,
    float4* __restrict__ vbuf, int CHI,
    const float* __restrict__ c1_w, __hip_bfloat16* __restrict__ w1b,
    const float* __restrict__ c2_w, __hip_bfloat16* __restrict__ w2t,
    const float* __restrict__ c3_w, __hip_bfloat16* __restrict__ w3t) {
    const int tid = threadIdx.x;
    int bx = blockIdx.x;

    if (bx < CHI) {                       // ---- halo zero for image bx ----
        const int b = bx;
        const uint4 z = {0u, 0u, 0u, 0u};
        uint4* a2 = act2 + (size_t)b * 17424;     // 33*33*128 bf16
        for (int i = tid; i < 528; i += 256) a2[i] = z;
        for (int i = tid; i < 512; i += 256) {
            int r = (i >> 4) + 1;
            a2[r * 528 + (i & 15)] = z;
        }
        int idx = b * 256 + tid;
        float4 zf = {0.f, 0.f, 0.f, 0.f};
        if (idx < 16384) vbuf[idx] = zf;
        return;
    }
    bx -= CHI;

    if (bx < 8) {                         // ---- conv1 weights [64][32] ----
        int t = bx * 256 + tid;           // t < 2048
        int k  = t & 31;
        int oc = t >> 5;
        w1b[t] = (k < 27) ? __float2bfloat16(c1_w[oc * 27 + k])
                          : __float2bfloat16(0.f);
        return;
    }
    bx -= 8;

    const float* src;
    __hip_bfloat16* dst;
    int O, C, t;
    if (bx < 288) {                       // ---- conv2 weights repack ----
        src = c2_w; dst = w2t; O = 128; C = 64;
        t = bx * 256 + tid;               // t < 73728
    } else {                              // ---- conv3 weights repack ----
        src = c3_w; dst = w3t; O = 256; C = 128;
        t = (bx - 288) * 256 + tid;       // t < 294912
    }
    int e   = t & 7;
    int r   = t >> 3;
    int n   = r % O;
    int q   = r / O;
    int SEG = C >> 3;
    int sg  = q % SEG;
    int tap = q / SEG;
    dst[t] = __float2bfloat16(src[(n * C + sg * 8 + e) * 9 + tap]);
}

// ---------------------------------------------------------------------------
// FUSED conv1+conv2: eliminates the 131MB act1 HBM round-trip.
// Per block (2 conv2-out rows x 32 ow, N=128 oc):
//  P0: DMA-stage input patch [3ch][11 rows][128 cols] fp32 (16.9 KB)
//  P1/P2: conv1 via im2col->Al->MFMA (two 256-px passes), relu+bias,
//         zero-masked halos, written into XOR-swizzled As[325px][64ch]
//  P3: conv2 K-loop + LDS epilogue (byte-identical to proven R8 code).
// LDS: sxf 16896 + Al 16384 + As 41600 = 74880 B -> 2 blocks/CU.
// ---------------------------------------------------------------------------
__global__ __launch_bounds__(256, 2) void conv12_fused_kernel(
    const float* __restrict__ in,
    const __hip_bfloat16* __restrict__ w1b,   // [64][32] bf16
    const float* __restrict__ bias1,
    const __hip_bfloat16* __restrict__ wtB,   // [tap][8][128][8]
    const float* __restrict__ bias2,
    __hip_bfloat16* __restrict__ out) {
    const int tid  = threadIdx.x;
    const int lane = tid & 63;
    const int wv   = tid >> 6;
    const int l15  = lane & 15;
    const int quad = lane >> 4;
    const int per  = gridDim.x >> 3;
    const int Mt   = (blockIdx.x & 7) * per + (blockIdx.x >> 3);
    const int bimg = Mt >> 4;
    const int oh0  = (Mt & 15) << 1;         // conv2 out rows oh0, oh0+1

    __shared__ __align__(16) char smem[74880];
    float*  sxf = (float*)smem;              // [3][11][128] fp32
    ushort* Al  = (ushort*)(smem + 16896);   // [256][32] bf16 swizzled
    ushort* As  = (ushort*)(smem + 33280);   // [325][64] bf16 chunk-swizzled
    ushort* Cs  = (ushort*)smem;             // epilogue alias (16896 B)

    const float* ip   = in + (size_t)bimg * 3 * 128 * 128;
    const int    row0 = 4 * oh0 - 3;         // input row of stage slot 0

    // P0: stage 3ch x 11 rows x 128 cols = 1056 16B chunks (rows clamped;
    // out-of-range rows are masked in the im2col, so clamp data is inert)
#pragma unroll
    for (int it = 0; it < 5; ++it) {
        int e = (it << 8) + tid;
        if (e < 1056) {
            int c = e / 352, rem = e - c * 352;
            int r = rem >> 5, k = rem & 31;
            int row = row0 + r;
            if (row < 0) row = 0;
            gload_lds16((const ushort*)(ip + c * 16384 + row * 128 + k * 4),
                        (ushort*)smem + (size_t)e * 8);
        }
    }
    __syncthreads();   // drains vmcnt -> input patch resident

    // conv1 weight fragment (4 KB table, L2-hot), live across both passes
    short8 af1[4];
#pragma unroll
    for (int i = 0; i < 4; ++i)
        af1[i] = __builtin_bit_cast(short8,
            *(const uint4*)(w1b + ((i * 16 + l15) * 32 + quad * 8)));
    float4 bv1[4];
#pragma unroll
    for (int i = 0; i < 4; ++i)
        bv1[i] = *(const float4*)(bias1 + i * 16 + quad * 4);

    // P1/P2: two conv1 passes over px0 = 0, 256 (global px = r2*65 + C)
    for (int px0 = 0; px0 < 325; px0 += 256) {
        const int pxg = px0 + tid;
        const int r2  = pxg / 65;
        const int C   = pxg - r2 * 65;
        const bool vpx = (pxg <= 324) && (C >= 1) && !(oh0 == 0 && r2 == 0);

        union { uint4 u4[4]; ushort us[32]; } rowv;
#pragma unroll
        for (int c = 0; c < 3; ++c)
#pragma unroll
            for (int kh = 0; kh < 3; ++kh) {
                const int ih = 4 * oh0 + 2 * r2 + kh - 3;
                const float* srow = sxf + (c * 11 + 2 * r2 + kh) * 128;
                const bool rok = (ih >= 0);
#pragma unroll
                for (int kw = 0; kw < 3; ++kw) {
                    int iw = 2 * C + kw - 3;
                    bool ok = vpx && rok && (iw >= 0);
                    float x = srow[iw < 0 ? 0 : iw];
                    rowv.us[c * 9 + kh * 3 + kw] = bf16_bits(ok ? x : 0.f);
                }
            }
#pragma unroll
        for (int k = 27; k < 32; ++k) rowv.us[k] = 0;
#pragma unroll
        for (int q = 0; q < 4; ++q)
            *(uint4*)(Al + tid * 32 + (((q ^ (tid >> 1)) & 3) << 3)) =
                rowv.u4[q];
        __syncthreads();   // Al ready

        short8 bf1[4];
#pragma unroll
        for (int j = 0; j < 4; ++j) {
            int pl = wv * 64 + j * 16 + l15;
            bf1[j] = __builtin_bit_cast(short8,
                *(const uint4*)(Al + pl * 32 + (((quad ^ (pl >> 1)) & 3) << 3)));
        }
        f32x4 acc1[4][4];
#pragma unroll
        for (int i = 0; i < 4; ++i)
#pragma unroll
            for (int j = 0; j < 4; ++j)
                acc1[i][j] = __builtin_amdgcn_mfma_f32_16x16x32_bf16(
                    af1[i], bf1[j], (f32x4){0.f, 0.f, 0.f, 0.f}, 0, 0, 0);

        // write D frags (col=px, row=oc) into As with the conv2 chunk swizzle
#pragma unroll
        for (int j = 0; j < 4; ++j) {
            int pg = px0 + wv * 64 + j * 16 + l15;
            if (pg <= 324) {
                int r2g = pg / 65;
                int Cg  = pg - r2g * 65;
                bool wv2 = (Cg >= 1) && !(oh0 == 0 && r2g == 0);
#pragma unroll
                for (int i = 0; i < 4; ++i) {
                    union { uint u; ushort us[2]; } lo, hi;
                    lo.us[0] = bf16_bits(wv2 ? fmaxf(acc1[i][j][0] +
                        ((const float*)&bv1[i])[0], 0.f) : 0.f);
                    lo.us[1] = bf16_bits(wv2 ? fmaxf(acc1[i][j][1] +
                        ((const float*)&bv1[i])[1], 0.f) : 0.f);
                    hi.us[0] = bf16_bits(wv2 ? fmaxf(acc1[i][j][2] +
                        ((const float*)&bv1[i])[2], 0.f) : 0.f);
                    hi.us[1] = bf16_bits(wv2 ? fmaxf(acc1[i][j][3] +
                        ((const float*)&bv1[i])[3], 0.f) : 0.f);
                    int qc = i * 2 + (quad >> 1);          // oc chunk
                    ushort* dst = As + pg * 64 +
                        ((qc ^ ((pg >> 1) & 7)) << 3) + (quad & 1) * 4;
                    *(uint*)dst = lo.u;
                    *(uint*)(dst + 2) = hi.u;
                }
            }
        }
        __syncthreads();   // As writes done; Al free for next pass
    }

    // P3: conv2 K-loop (byte-identical structure to proven R8 kernel)
    f32x4 acc[2][4];
#pragma unroll
    for (int i = 0; i < 2; ++i)
#pragma unroll
        for (int j = 0; j < 4; ++j) acc[i][j] = (f32x4){0.f, 0.f, 0.f, 0.f};

    const int pxw2 = (wv >> 1) << 5;         // wave owns 32 px
    const int wn   = (wv & 1) << 6;          // wave owns 64 oc

    for (int h = 0; h < 2; ++h) {
        const int q = h * 4 + quad;          // logical K-seg (8 ch each)
#pragma unroll
        for (int tap = 0; tap < 9; ++tap) {
            const int kh = tap / 3, kw = tap - kh * 3;
            short8 af[2], bf[4];
#pragma unroll
            for (int i = 0; i < 2; ++i) {    // A = pixels (32 per wave)
                int ml = pxw2 + i * 16 + l15;
                int p  = ((ml >> 5) * 2 + kh) * 65 + ((ml & 31) * 2 + kw);
                af[i] = __builtin_bit_cast(short8,
                    *(const uint4*)(As + p * 64 +
                                    ((q ^ ((p >> 1) & 7)) << 3)));
            }
#pragma unroll
            for (int j = 0; j < 4; ++j)      // B = weights (64 oc per wave)
                bf[j] = __builtin_bit_cast(short8,
                    *(const uint4*)(wtB +
                        ((size_t)((tap * 8 + h * 4 + quad) * 128) +
                         wn + j * 16 + l15) * 8));
#pragma unroll
            for (int i = 0; i < 2; ++i)
#pragma unroll
                for (int j = 0; j < 4; ++j)
                    acc[i][j] = __builtin_amdgcn_mfma_f32_16x16x32_bf16(
                        af[i], bf[j], acc[i][j], 0, 0, 0);
        }
    }

    // epilogue: bias+ReLU -> bf16 tile in LDS (alias sxf) -> coalesced stores
    __syncthreads();
#pragma unroll
    for (int j = 0; j < 4; ++j) {
        int n = wn + j * 16 + l15;
        float bv = bias2[n];
#pragma unroll
        for (int i = 0; i < 2; ++i)
#pragma unroll
            for (int r = 0; r < 4; ++r) {
                int ml = pxw2 + i * 16 + quad * 4 + r;   // px 0..63
                Cs[ml * 132 + n] = bf16_bits(fmaxf(acc[i][j][r] + bv, 0.f));
            }
    }
    __syncthreads();
#pragma unroll
    for (int q2 = 0; q2 < 8; ++q2) {
        int c   = tid + 256 * q2;
        int row = c >> 5;
        int off = c & 31;
        uint2 val = *(const uint2*)(Cs + row * 132 + off * 4);
        int m  = (Mt << 6) + row;
        int b  = m >> 10;
        int rr = m & 1023;
        int oh = rr >> 5;
        int ow = rr & 31;
        size_t pix = ((size_t)(b * 33 + oh + 1) * 33 + (ow + 1));
        *(uint2*)(out + pix * 128 + off * 4) = val;
    }
}

// ---------------------------------------------------------------------------
// conv3 implicit-GEMM + fused pool (round-4 proven version).
// ---------------------------------------------------------------------------
__global__ __launch_bounds__(256, 2) void conv3_gemm_pool_kernel(
    const __hip_bfloat16* __restrict__ act,
    const __hip_bfloat16* __restrict__ wtB,   // [tap][16][256][8]
    const float* __restrict__ bias,
    float* __restrict__ v /* [CHI,256], pre-zeroed */) {
    const int tid  = threadIdx.x;
    const int lane = tid & 63;
    const int w    = tid >> 6;
    const int l15  = lane & 15;
    const int quad = lane >> 4;
    const int per  = gridDim.x >> 3;
    const int Mt   = (blockIdx.x & 7) * per + (blockIdx.x >> 3);
    const int bimg = Mt >> 2;
    const int oh0  = (Mt & 3) << 2;

    __shared__ __align__(16) char smem[77824];
    ushort* As   = (ushort*)smem;
    float*  sred = (float*)smem;                 // pool alias (1 KB)

    f32x4 acc[4][4];
#pragma unroll
    for (int i = 0; i < 4; ++i)
#pragma unroll
        for (int j = 0; j < 4; ++j) acc[i][j] = (f32x4){0.f, 0.f, 0.f, 0.f};

    const int wn = w << 6;                       // wave owns 64 n-cols
    const size_t abase = ((size_t)(bimg * 33 + 2 * oh0)) * 33 * 128;
    const ushort* ap = (const ushort*)act;

#pragma unroll
    for (int it = 0; it < 19; ++it) {
        int c  = (it << 8) + tid;
        int p  = c >> 4;
        int t  = c & 15;
        int h  = t >> 3;
        int ss = (t & 7) ^ ((p >> 1) & 7);
        gload_lds16(ap + abase + (size_t)p * 128 + h * 64 + ss * 8,
                    As + (size_t)c * 8);
    }
    __syncthreads();

    for (int h = 0; h < 2; ++h) {
#pragma unroll 1
        for (int tap = 0; tap < 9; ++tap) {
            const int kh = tap / 3, kw = tap - kh * 3;
#pragma unroll
            for (int ks = 0; ks < 2; ++ks) {
                short8 af[4], bf[4];
                const int sl = ks * 4 + quad;
#pragma unroll
                for (int i = 0; i < 4; ++i) {
                    int p = (i * 2 + kh) * 33 + l15 * 2 + kw;
                    af[i] = __builtin_bit_cast(short8,
                        *(const uint4*)(As + p * 128 + h * 64 +
                                        (((sl ^ (p >> 1)) & 7) << 3)));
                }
#pragma unroll
                for (int j = 0; j < 4; ++j)
                    bf[j] = __builtin_bit_cast(short8,
                        *(const uint4*)(wtB +
                            ((size_t)((tap * 16 + h * 8 + sl) * 256) +
                             wn + j * 16 + l15) * 8));
#pragma unroll
                for (int i = 0; i < 4; ++i)
#pragma unroll
                    for (int j = 0; j < 4; ++j)
                        acc[i][j] = __builtin_amdgcn_mfma_f32_16x16x32_bf16(
                            af[i], bf[j], acc[i][j], 0, 0, 0);
            }
        }
    }

    float s4[4];
#pragma unroll
    for (int j = 0; j < 4; ++j) {
        float bv = bias[wn + j * 16 + l15];
        float s = 0.f;
#pragma unroll
        for (int i = 0; i < 4; ++i)
#pragma unroll
            for (int r = 0; r < 4; ++r)
                s += fmaxf(acc[i][j][r] + bv, 0.f);
        s += __shfl_xor(s, 16, 64);
        s += __shfl_xor(s, 32, 64);
        s4[j] = s;
    }
    __syncthreads();
    if (quad == 0) {
#pragma unroll
        for (int j = 0; j < 4; ++j) sred[wn + j * 16 + l15] = s4[j];
    }
    __syncthreads();
    atomicAdd(v + (size_t)bimg * 256 + tid, sred[tid] * (1.f / 256.f));
}

// ---------------------------------------------------------------------------
// Tail: one block (256 thr) per sample; K-split GEMV stages, float4 weights.
// ---------------------------------------------------------------------------
template<int N, int K, int S, bool RELU>
__device__ __forceinline__ void gemv_stage(const float* __restrict__ w,
                                           const float* __restrict__ bias,
                                           const float* in, float* outv,
                                           float4* red4, int tid) {
    constexpr int G = N / 4;
    constexpr int CHK = K / S;
    static_assert(G * S == 256 && CHK * S == K, "stage shape");
    const int g = tid % G, s = tid / G;
    const float4* wp = (const float4*)w;
    float4 a; a.x = a.y = a.z = a.w = 0.f;
    const int k0 = s * CHK;
#pragma unroll 8
    for (int i = 0; i < CHK; ++i) {
        float x = in[k0 + i];
        float4 wv = wp[(size_t)(k0 + i) * G + g];
        a.x = fmaf(x, wv.x, a.x);
        a.y = fmaf(x, wv.y, a.y);
        a.z = fmaf(x, wv.z, a.z);
        a.w = fmaf(x, wv.w, a.w);
    }
    red4[tid] = a;
    __syncthreads();
    if (tid < N) {
        int gg = tid >> 2, e = tid & 3;
        float vv = bias[tid];
#pragma unroll
        for (int ss = 0; ss < S; ++ss) {
            const float* rp = (const float*)(red4 + ss * G + gg);
            vv += rp[e];
        }
        if (RELU) vv = fmaxf(vv, 0.f);
        outv[tid] = vv;
    }
    __syncthreads();
}

__global__ __launch_bounds__(256) void tail_kernel(
    const float* __restrict__ prop, const int* __restrict__ task_ids,
    const float* __restrict__ p1_w, const float* __restrict__ p1_b,
    const float* __restrict__ p2_w, const float* __restrict__ p2_b,
    const float* __restrict__ v,
    const float* __restrict__ f1_w, const float* __restrict__ f1_b,
    const float* __restrict__ f2_w, const float* __restrict__ f2_b,
    const float* __restrict__ task_emb,
    const float* __restrict__ g_w, const float* __restrict__ g_b,
    const float* __restrict__ h1_w, const float* __restrict__ h1_b,
    const float* __restrict__ h2_w, const float* __restrict__ h2_b,
    const float* __restrict__ h3_w, const float* __restrict__ h3_b,
    float* __restrict__ out) {
    const int b   = blockIdx.x;
    const int tid = threadIdx.x;
    const int t   = task_ids[b];
    __shared__ float sa[320];
    __shared__ float sb[288];
    __shared__ float sph[64];
    __shared__ float4 red4[256];

    sa[tid] = (tid < 256) ? v[(size_t)b * 256 + tid] : 0.f;
    if (tid < 64) {
        float h = p1_b[tid];
#pragma unroll
        for (int k = 0; k < 7; ++k) h = fmaf(prop[b * 7 + k], p1_w[k * 64 + tid], h);
        sph[tid] = fmaxf(h, 0.f);
    }
    __syncthreads();
    gemv_stage<64, 64, 16, false>(p2_w, p2_b, sph, sa + 256, red4, tid);
    gemv_stage<256, 320, 4, true>(f1_w, f1_b, sa, sb, red4, tid);
    gemv_stage<256, 256, 4, true>(f2_w, f2_b, sb, sa, red4, tid);
    if (tid < 32) sa[256 + tid] = task_emb[t * 32 + tid];
    __syncthreads();
    gemv_stage<256, 288, 4, true>(g_w, g_b, sa, sb, red4, tid);
    gemv_stage<128, 256, 8, true>(h1_w + (size_t)t * 32768, h1_b + t * 128,
                                  sb, sa, red4, tid);
    gemv_stage<128, 128, 8, true>(h2_w + (size_t)t * 16384, h2_b + t * 128,
                                  sa, sb, red4, tid);
    if (tid < 128) {
        float4 wv = ((const float4*)(h3_w + (size_t)t * 512))[tid];
        float x = sb[tid];
        float r0 = x * wv.x, r1 = x * wv.y, r2 = x * wv.z, r3 = x * wv.w;
#pragma unroll
        for (int off = 1; off < 64; off <<= 1) {
            r0 += __shfl_xor(r0, off, 64);
            r1 += __shfl_xor(r1, off, 64);
            r2 += __shfl_xor(r2, off, 64);
            r3 += __shfl_xor(r3, off, 64);
        }
        if ((tid & 63) == 0) {
            float4 rv; rv.x = r0; rv.y = r1; rv.z = r2; rv.w = r3;
            red4[tid >> 6] = rv;
        }
    }
    __syncthreads();
    if (tid < 4) {
        const float* ra = (const float*)(red4 + 0);
        const float* rb = (const float*)(red4 + 1);
        out[b * 4 + tid] = ra[tid] + rb[tid] + h3_b[t * 4 + tid];
    }
}

// ---------------------------------------------------------------------------
extern "C" void kernel_launch(void* const* d_in, const int* in_sizes, int n_in,
                              void* d_out, int out_size, void* d_ws, size_t ws_size,
                              hipStream_t stream) {
    (void)in_sizes; (void)n_in; (void)out_size;
    const float* images   = (const float*)d_in[0];
    const float* prop     = (const float*)d_in[1];
    const int*   task_ids = (const int*)d_in[2];
    const float* c1_w = (const float*)d_in[3];
    const float* c1_b = (const float*)d_in[4];
    const float* c2_w = (const float*)d_in[5];
    const float* c2_b = (const float*)d_in[6];
    const float* c3_w = (const float*)d_in[7];
    const float* c3_b = (const float*)d_in[8];
    const float* p1_w = (const float*)d_in[9];
    const float* p1_b = (const float*)d_in[10];
    const float* p2_w = (const float*)d_in[11];
    const float* p2_b = (const float*)d_in[12];
    const float* f1_w = (const float*)d_in[13];
    const float* f1_b = (const float*)d_in[14];
    const float* f2_w = (const float*)d_in[15];
    const float* f2_b = (const float*)d_in[16];
    const float* temb = (const float*)d_in[17];
    const float* g_w  = (const float*)d_in[18];
    const float* g_b  = (const float*)d_in[19];
    const float* h1_w = (const float*)d_in[20];
    const float* h1_b = (const float*)d_in[21];
    const float* h2_w = (const float*)d_in[22];
    const float* h2_b = (const float*)d_in[23];
    const float* h3_w = (const float*)d_in[24];
    const float* h3_b = (const float*)d_in[25];
    float* out = (float*)d_out;

    const size_t per_img = (size_t)65 * 65 * 64 * 2 + (size_t)33 * 33 * 128 * 2;
    const size_t fixed   = (size_t)256 * 256 * 4 + 1728 * 4 +
                           (size_t)73728 * 2 + (size_t)294912 * 2 + 4096;
    int CHI = 64;
    if (ws_size >= fixed + per_img * 256) CHI = 256;
    else if (ws_size >= fixed + per_img * 128) CHI = 128;

    char* ws = (char*)d_ws;
    size_t off = 0;
    auto alloc = [&](size_t bytes) {
        void* p = ws + off;
        off += (bytes + 255) & ~(size_t)255;
        return p;
    };
    // act1 slot retained in layout (unused) to keep CHI thresholds identical
    (void)alloc((size_t)CHI * 65 * 65 * 64 * 2);
    __hip_bfloat16* act2 = (__hip_bfloat16*)alloc((size_t)CHI * 33 * 33 * 128 * 2);
    float*          vbuf = (float*)alloc((size_t)256 * 256 * 4);
    __hip_bfloat16* w1b  = (__hip_bfloat16*)alloc((size_t)2048 * 2);
    __hip_bfloat16* w2t  = (__hip_bfloat16*)alloc((size_t)73728 * 2);
    __hip_bfloat16* w3t  = (__hip_bfloat16*)alloc((size_t)294912 * 2);

    prep_kernel<<<dim3(CHI + 8 + 288 + 1152), 256, 0, stream>>>(
        (uint4*)act2, (float4*)vbuf, CHI,
        c1_w, w1b, c2_w, w2t, c3_w, w3t);

    for (int c0 = 0; c0 < 256; c0 += CHI) {
        const float* img_c = images + (size_t)c0 * 3 * 128 * 128;
        conv12_fused_kernel<<<dim3(CHI * 16), 256, 0, stream>>>(
            img_c, w1b, c1_b, w2t, c2_b, act2);
        conv3_gemm_pool_kernel<<<dim3(CHI * 4), 256, 0, stream>>>(
            act2, w3t, c3_b, vbuf + (size_t)c0 * 256);
    }
    tail_kernel<<<256, 256, 0, stream>>>(prop, task_ids, p1_w, p1_b, p2_w, p2_b,
                                         vbuf, f1_w, f1_b, f2_w, f2_b, temb,
                                         g_w, g_b, h1_w, h1_b, h2_w, h2_b,
                                         h3_w, h3_b, out);
}